// Round 6
// baseline (1789.987 us; speedup 1.0000x reference)
//
#include <hip/hip_runtime.h>
#include <stdint.h>
#include <stddef.h>

// ---------------------------------------------------------------------------
// DiffusionActionHead: fused 10-step DDPM sampler, bf16 MFMA, round 6.
// MTILE=32 rows/block, 256 threads (4 waves), 3 blocks/CU (LDS 48.5 KB).
// cond lives in LDS (B-frag order) for all 10 steps; activations ping-pong
// between two frag-ordered LDS buffers; residual read back from own cells.
// Per-wave: 64 features x 32 rows = acc[8] (32 VGPRs) -> live set ~80, no spill.
// ---------------------------------------------------------------------------

typedef __bf16 bf16_t;
typedef __bf16 bf16x8 __attribute__((ext_vector_type(8)));
typedef __bf16 bf16x4 __attribute__((ext_vector_type(4)));
typedef float  f32x4  __attribute__((ext_vector_type(4)));

constexpr int KP = 264;   // LDS row stride for cond_kernel staging only

// ---------------- exact-erf GELU (A&S 7.1.26, |err|<1.5e-7) ----------------
__device__ __forceinline__ float gelu_f(float x) {
  float z  = 0.70710678f * x;
  float az = fabsf(z);
  float t  = __builtin_amdgcn_rcpf(fmaf(0.3275911f, az, 1.0f));
  float e  = __expf(-az * az);
  float p  = fmaf(1.061405429f, t, -1.453152027f);
  p = fmaf(p, t, 1.421413741f);
  p = fmaf(p, t, -0.284496736f);
  p = fmaf(p, t, 0.254829592f);
  float er = fmaf(-(p * t), e, 1.0f);   // erf(|z|)
  er = copysignf(er, z);
  return 0.5f * x * (1.0f + er);
}

// ---------------- JAX threefry2x32 (20 rounds) ------------------------------
#define TFR(a) x0 += x1; x1 = (x1 << (a)) | (x1 >> (32 - (a))); x1 ^= x0;
__device__ __forceinline__ void tf2(uint32_t k0, uint32_t k1,
                                    uint32_t x0, uint32_t x1,
                                    uint32_t& o0, uint32_t& o1) {
  uint32_t k2 = k0 ^ k1 ^ 0x1BD11BDAu;
  x0 += k0; x1 += k1;
  TFR(13) TFR(15) TFR(26) TFR(6)
  x0 += k1; x1 += k2 + 1u;
  TFR(17) TFR(29) TFR(16) TFR(24)
  x0 += k2; x1 += k0 + 2u;
  TFR(13) TFR(15) TFR(26) TFR(6)
  x0 += k0; x1 += k1 + 3u;
  TFR(17) TFR(29) TFR(16) TFR(24)
  x0 += k1; x1 += k2 + 4u;
  TFR(13) TFR(15) TFR(26) TFR(6)
  x0 += k2; x1 += k0 + 5u;
  o0 = x0; o1 = x1;
}
#undef TFR

// uniform bits -> N(0,1) exactly like jax.random.normal (XLA erfinv poly)
__device__ __forceinline__ float nrm_from_bits(uint32_t bits) {
  float f = __uint_as_float((bits >> 9) | 0x3f800000u) - 1.0f;  // [0,1)
  const float lo = -0.99999994f;
  float u = fmaxf(lo, __fadd_rn(__fmul_rn(f, 2.0f), lo));
  float w = -log1pf(-__fmul_rn(u, u));
  float p;
  if (w < 5.0f) {
    float ww = w - 2.5f;
    p = 2.81022636e-08f;
    p = fmaf(p, ww, 3.43273939e-07f);
    p = fmaf(p, ww, -3.5233877e-06f);
    p = fmaf(p, ww, -4.39150654e-06f);
    p = fmaf(p, ww, 0.00021858087f);
    p = fmaf(p, ww, -0.00125372503f);
    p = fmaf(p, ww, -0.00417768164f);
    p = fmaf(p, ww, 0.246640727f);
    p = fmaf(p, ww, 1.50140941f);
  } else {
    float ww = sqrtf(w) - 3.0f;
    p = -0.000200214257f;
    p = fmaf(p, ww, 0.000100950558f);
    p = fmaf(p, ww, 0.00134934322f);
    p = fmaf(p, ww, -0.00367342844f);
    p = fmaf(p, ww, 0.00573950773f);
    p = fmaf(p, ww, -0.0076224613f);
    p = fmaf(p, ww, 0.00943887047f);
    p = fmaf(p, ww, 1.00167406f);
    p = fmaf(p, ww, 2.83297682f);
  }
  return 1.41421354f * (p * u);
}

// ---------------- kernel 1: weight repack (A-frag order, m=feature) --------
__global__ void wprep_kernel(const float* __restrict__ condw,
                             const float* __restrict__ w1,
                             const float* __restrict__ skw,
                             const float* __restrict__ w2,
                             const float* __restrict__ bw1,
                             const float* __restrict__ bw2,
                             bf16_t* __restrict__ wts) {
  int e = blockIdx.x * 256 + threadIdx.x;
  int m = e >> 16;
  int r = e & 65535;
  int nt = r >> 12, kc = (r >> 9) & 7, lane = (r >> 3) & 63, j = r & 7;
  int n = nt * 16 + (lane & 15);
  int k = kc * 32 + (lane >> 4) * 8 + j;
  const float* src;
  if      (m == 0) src = condw;
  else if (m == 1) src = w1;                    // blk0_w1 rows 0..255 (cond)
  else if (m == 2) src = skw;                   // blk0_skip_w rows 0..255
  else if (m == 3) src = w2;                    // blk0_w2
  else if (m <= 6) src = bw1 + (m - 4) * 65536; // blks_w1[i]
  else             src = bw2 + (m - 7) * 65536; // blks_w2[i]
  wts[e] = (bf16_t)src[k * 256 + n];
}

// ---------------- kernel 1b: final_w A-frags (m=action, 12 cols zero) ------
__global__ void ffp_kernel(const float* __restrict__ fw, bf16_t* __restrict__ fwf) {
  int e = blockIdx.x * 256 + threadIdx.x;   // 4096 elems: [kc 8][lane 64][j 8]
  if (e >= 4096) return;
  int kc = e >> 9, lane = (e >> 3) & 63, j = e & 7;
  int l16 = lane & 15, q = lane >> 4;
  int k = kc * 32 + q * 8 + j;
  fwf[e] = (l16 < 4) ? (bf16_t)fw[k * 4 + l16] : (bf16_t)0.0f;
}

// ---------------- kernel 2: per-step vectors + scalars ---------------------
__global__ void prep_kernel(const float* __restrict__ time_w,
                            const float* __restrict__ time_b,
                            const float* __restrict__ w1,
                            const float* __restrict__ b1,
                            const float* __restrict__ skw,
                            const float* __restrict__ skb,
                            float* __restrict__ tvecs,
                            float* __restrict__ stepsc) {
  int s = blockIdx.x;          // 0..9, t = 90 - 10*s
  int j = threadIdx.x;
  int t = 90 - s * 10;
  float tval = (float)t;
  __shared__ float emb[256];
  __shared__ float temb[256];
  if (j < 128) {
    float freq = expf((float)j * -0.07252236513366287f);  // -ln(1e4)/127
    float e = tval * freq;
    emb[j] = sinf(e);
    emb[j + 128] = cosf(e);
  }
  __syncthreads();
  float a = time_b[j];
  for (int k = 0; k < 256; ++k) a = fmaf(emb[k], time_w[k * 256 + j], a);
  temb[j] = gelu_f(a);
  __syncthreads();
  float v1 = b1[j], v2 = skb[j];
  for (int k = 0; k < 256; ++k) {
    float tk = temb[k];
    v1 = fmaf(tk, w1[(256 + k) * 256 + j], v1);    // blk0_w1 rows 256..511
    v2 = fmaf(tk, skw[(256 + k) * 256 + j], v2);   // blk0_skip_w rows 256..511
  }
  tvecs[s * 512 + j] = v1;
  tvecs[s * 512 + 256 + j] = v2;
  if (j == 0) {
    float step = (0.02f - 1e-4f) / 99.0f;
    float acp = 1.0f, beta = 0.0f;
    for (int i = 0; i <= t; ++i) {
      beta = fmaf((float)i, step, 1e-4f);
      acp *= (1.0f - beta);
    }
    stepsc[s * 4 + 0] = 1.0f / sqrtf(1.0f - beta);   // 1/sqrt(alpha)
    stepsc[s * 4 + 1] = beta / sqrtf(1.0f - acp);    // b/sqrt(1-acp)
    stepsc[s * 4 + 2] = (t > 0) ? sqrtf(beta) : 0.0f;
    stepsc[s * 4 + 3] = 0.0f;
  }
}

// ---------------- kernel 3: x0 + noises (partitionable threefry) -----------
__global__ void noise_kernel(float* __restrict__ xout, float* __restrict__ nout, int nb) {
  int gid = blockIdx.x * 256 + threadIdx.x;
  int nx = nb * 4;
  int nn = nb * 40;
  uint32_t k0, k1, o0, o1;
  if (gid < nx) {
    tf2(0u, 42u, 0u, 999u, k0, k1);                 // fold_in(key(42), 999)
    tf2(k0, k1, 0u, (uint32_t)gid, o0, o1);
    xout[gid] = nrm_from_bits(o0 ^ o1);
  } else if (gid < nx + nn) {
    int i = gid - nx;
    tf2(0u, 42u, 0u, 7u, k0, k1);                   // fold_in(key(42), 7)
    tf2(k0, k1, 0u, (uint32_t)i, o0, o1);
    nout[i] = nrm_from_bits(o0 ^ o1);
  }
}

// ---------------- kernel 4: cond GEMM -> condf (32-row-granule frag order) -
// condf[g][kc 8][nt 2][lane 64][j 8], g = global row / 32:
//   element = cond[row = g*32 + nt*16 + (lane&15)][k = kc*32 + (lane>>4)*8 + j]
__global__ __launch_bounds__(256, 2) void cond_kernel(
    const float* __restrict__ feat, const bf16_t* __restrict__ wts,
    const float* __restrict__ condb, bf16_t* __restrict__ condf) {
  __shared__ __align__(16) bf16_t la[64 * KP];
  const int tid = threadIdx.x;
  const int wave = tid >> 6, lane = tid & 63, quad = lane >> 4, l16 = lane & 15;
  const int rowbase = blockIdx.x * 64;
  for (int it = 0; it < 16; ++it) {
    int e = (it * 256 + tid) * 4;
    int rr = e >> 8, c = e & 255;
    f32x4 v = *(const f32x4*)(feat + (size_t)(rowbase + rr) * 256 + c);
    bf16x4 bv;
    bv[0] = (bf16_t)v[0]; bv[1] = (bf16_t)v[1];
    bv[2] = (bf16_t)v[2]; bv[3] = (bf16_t)v[3];
    *(bf16x4*)(la + rr * KP + c) = bv;
  }
  __syncthreads();
  // A = cond rows (m=batch), B = weights (n=feature)
  f32x4 acc[16];
  #pragma unroll
  for (int i = 0; i < 16; ++i) acc[i] = f32x4{0.f, 0.f, 0.f, 0.f};
  const bf16_t* A = la + l16 * KP + quad * 8;
  const bf16_t* Wp = wts + wave * 16384 + lane * 8;
  #pragma unroll 2
  for (int kc = 0; kc < 8; ++kc) {
    bf16x8 a[4], b[4];
    #pragma unroll
    for (int rt = 0; rt < 4; ++rt) a[rt] = *(const bf16x8*)(A + rt * 16 * KP + kc * 32);
    #pragma unroll
    for (int ct = 0; ct < 4; ++ct) b[ct] = *(const bf16x8*)(Wp + ct * 4096 + kc * 512);
    #pragma unroll
    for (int rt = 0; rt < 4; ++rt)
      #pragma unroll
      for (int ct = 0; ct < 4; ++ct)
        acc[rt * 4 + ct] =
            __builtin_amdgcn_mfma_f32_16x16x32_bf16(a[rt], b[ct], acc[rt * 4 + ct], 0, 0, 0);
  }
  float bc[4];
  #pragma unroll
  for (int ct = 0; ct < 4; ++ct) bc[ct] = condb[wave * 64 + ct * 16 + l16];
  #pragma unroll
  for (int rt = 0; rt < 4; ++rt)
    #pragma unroll
    for (int r = 0; r < 4; ++r) {
      // batch row64 = rt*16 + quad*4 + r -> granule rt>>1, nt = rt&1
      size_t gbase = ((size_t)blockIdx.x * 2 + (rt >> 1)) * 8192 + (size_t)(rt & 1) * 512;
      int rowin16 = quad * 4 + r;
      #pragma unroll
      for (int ct = 0; ct < 4; ++ct) {
        int f = wave * 64 + ct * 16 + l16;     // feature = k index
        condf[gbase + (size_t)(f >> 5) * 1024 + (((f >> 3) & 3) * 16 + rowin16) * 8 + (f & 7)] =
            (bf16_t)(acc[rt * 4 + ct][r] + bc[ct]);
      }
    }
}

// ---------------- kernel 5: fused 10-step sampler (MTILE=32) ---------------
__global__ __launch_bounds__(256, 3) void fused_kernel(
    const bf16_t* __restrict__ condf, const bf16_t* __restrict__ wts,
    const bf16_t* __restrict__ fwf,
    const float* __restrict__ tvecs, const float* __restrict__ stepsc,
    const float* __restrict__ x0w, const float* __restrict__ noises,
    const float* __restrict__ w1bot, const float* __restrict__ skipbot,
    const float* __restrict__ b2v, const float* __restrict__ blksb1,
    const float* __restrict__ blksb2, const float* __restrict__ finalb,
    float* __restrict__ out, int nb) {
  // all in B-frag order [kc(8)][nt(2)][lane(64)][j(8)] = 8192 bf16 = 16 KB
  __shared__ __align__(16) bf16_t condL[8192];
  __shared__ __align__(16) bf16_t bufY[8192];
  __shared__ __align__(16) bf16_t bufH[8192];
  __shared__ __align__(16) float  lx[128];
  const int tid = threadIdx.x;
  const int w = tid >> 6, lane = tid & 63, q = lane >> 4, l16 = lane & 15;
  const int rowbase = blockIdx.x * 32;
  const int myrow = w * 16 + l16;          // valid for waves 0,1 (head/x path)

  // stage cond tile (16 KB, contiguous & coalesced) + x0
  {
    const bf16_t* src = condf + (size_t)blockIdx.x * 8192;
    #pragma unroll
    for (int it = 0; it < 4; ++it) {
      int e = (it * 256 + tid) * 8;
      *(bf16x8*)(condL + e) = *(const bf16x8*)(src + e);
    }
    if (w < 2 && q == 0)
      *(f32x4*)(lx + myrow * 4) = *(const f32x4*)(x0w + (size_t)(rowbase + myrow) * 4);
  }
  __syncthreads();

  f32x4 acc[8];   // [mt 4][nt 2]

  // own-cell offsets: cell (mt,nt): features f0..f0+3 (f0 = w*64+mt*16+q*4),
  // rows nt*16+l16 -> elem offset (f0>>5)*1024 + nt*512 + (((f0>>3)&3)*16+l16)*8 + (f0&7)
  int soff[4];
  #pragma unroll
  for (int mt = 0; mt < 4; ++mt) {
    int f0 = w * 64 + mt * 16 + q * 4;
    soff[mt] = (f0 >> 5) * 1024 + (((f0 >> 3) & 3) * 16 + l16) * 8 + (f0 & 7);
  }

  auto gemm = [&](const bf16_t* wl, const bf16_t* act) {
    #pragma unroll
    for (int i = 0; i < 8; ++i) acc[i] = f32x4{0.f, 0.f, 0.f, 0.f};
    #pragma unroll
    for (int kc = 0; kc < 8; ++kc) {
      bf16x8 a[4], b[2];
      #pragma unroll
      for (int nt = 0; nt < 2; ++nt)
        b[nt] = *(const bf16x8*)(act + kc * 1024 + nt * 512 + lane * 8);
      #pragma unroll
      for (int mt = 0; mt < 4; ++mt)
        a[mt] = *(const bf16x8*)(wl + mt * 4096 + kc * 512);
      #pragma unroll
      for (int mt = 0; mt < 4; ++mt)
        #pragma unroll
        for (int nt = 0; nt < 2; ++nt)
          acc[mt * 2 + nt] =
              __builtin_amdgcn_mfma_f32_16x16x32_bf16(a[mt], b[nt], acc[mt * 2 + nt], 0, 0, 0);
    }
  };
  auto store_act = [&](bf16_t* buf) {
    #pragma unroll
    for (int mt = 0; mt < 4; ++mt)
      #pragma unroll
      for (int nt = 0; nt < 2; ++nt) {
        f32x4 v = acc[mt * 2 + nt];
        bf16x4 bv;
        bv[0] = (bf16_t)v[0]; bv[1] = (bf16_t)v[1];
        bv[2] = (bf16_t)v[2]; bv[3] = (bf16_t)v[3];
        *(bf16x4*)(buf + soff[mt] + nt * 512) = bv;
      }
  };
  // acc += tvec + x @ Wbot (exact f32 x-path); optional gelu
  auto epi_bot = [&](const float* tv, const float* bot, bool dogelu) {
    f32x4 xr[2];
    #pragma unroll
    for (int nt = 0; nt < 2; ++nt) xr[nt] = *(const f32x4*)(lx + (nt * 16 + l16) * 4);
    #pragma unroll
    for (int mt = 0; mt < 4; ++mt) {
      int m = w * 64 + mt * 16 + q * 4;
      f32x4 tq = *(const f32x4*)(tv + m);
      f32x4 b0 = *(const f32x4*)(bot + m);
      f32x4 b1 = *(const f32x4*)(bot + 256 + m);
      f32x4 b2 = *(const f32x4*)(bot + 512 + m);
      f32x4 b3 = *(const f32x4*)(bot + 768 + m);
      #pragma unroll
      for (int nt = 0; nt < 2; ++nt)
        #pragma unroll
        for (int r = 0; r < 4; ++r) {
          float v = acc[mt * 2 + nt][r] + tq[r];
          v = fmaf(xr[nt][0], b0[r], v);
          v = fmaf(xr[nt][1], b1[r], v);
          v = fmaf(xr[nt][2], b2[r], v);
          v = fmaf(xr[nt][3], b3[r], v);
          acc[mt * 2 + nt][r] = dogelu ? gelu_f(v) : v;
        }
    }
  };
  auto epi_gelu = [&](const float* bias) {
    #pragma unroll
    for (int mt = 0; mt < 4; ++mt) {
      f32x4 bb = *(const f32x4*)(bias + w * 64 + mt * 16 + q * 4);
      #pragma unroll
      for (int nt = 0; nt < 2; ++nt)
        #pragma unroll
        for (int r = 0; r < 4; ++r)
          acc[mt * 2 + nt][r] = gelu_f(acc[mt * 2 + nt][r] + bb[r]);
    }
  };
  // h = gelu(acc + bias) + resid, resid read back from own cells of `buf`
  auto epi_gelu_res = [&](const float* bias, const bf16_t* buf) {
    #pragma unroll
    for (int mt = 0; mt < 4; ++mt) {
      f32x4 bb = *(const f32x4*)(bias + w * 64 + mt * 16 + q * 4);
      #pragma unroll
      for (int nt = 0; nt < 2; ++nt) {
        bf16x4 rv = *(const bf16x4*)(buf + soff[mt] + nt * 512);
        #pragma unroll
        for (int r = 0; r < 4; ++r)
          acc[mt * 2 + nt][r] = gelu_f(acc[mt * 2 + nt][r] + bb[r]) + (float)rv[r];
      }
    }
  };

  for (int s = 0; s < 10; ++s) {
    const float* tw  = tvecs + s * 512;
    const float* tsk = tw + 256;

    // y1 = gelu(W1_top·cond + tw1 + x·W1_bot)          -> bufY
    gemm(wts + 1 * 65536 + (size_t)w * 16384 + lane * 8, condL);
    epi_bot(tw, w1bot, true);
    store_act(bufY);
    // skip = Wskip_top·cond + tskip + x·Wskip_bot      -> bufH (bf16)
    gemm(wts + 2 * 65536 + (size_t)w * 16384 + lane * 8, condL);
    epi_bot(tsk, skipbot, false);
    store_act(bufH);
    __syncthreads();
    // h = gelu(W2·y1 + b2) + skip                      -> bufH (own cells)
    gemm(wts + 3 * 65536 + (size_t)w * 16384 + lane * 8, bufY);
    epi_gelu_res(b2v, bufH);
    store_act(bufH);
    __syncthreads();
    // blocks 1..3: h = gelu(W2·gelu(W1·h + b1) + b2) + h
    #pragma unroll 1
    for (int blk = 0; blk < 3; ++blk) {
      gemm(wts + (size_t)(4 + blk) * 65536 + (size_t)w * 16384 + lane * 8, bufH);
      epi_gelu(blksb1 + blk * 256);
      store_act(bufY);
      __syncthreads();
      gemm(wts + (size_t)(7 + blk) * 65536 + (size_t)w * 16384 + lane * 8, bufY);
      epi_gelu_res(blksb2 + blk * 256, bufH);
      store_act(bufH);
      __syncthreads();
    }
    // head: pred = final_w^T · h (waves 0,1 only: B = bufH frag nt=w)
    if (w < 2) {
      f32x4 ph = f32x4{0.f, 0.f, 0.f, 0.f};
      #pragma unroll
      for (int kc = 0; kc < 8; ++kc) {
        bf16x8 afw = *(const bf16x8*)(fwf + kc * 512 + lane * 8);
        bf16x8 hh  = *(const bf16x8*)(bufH + kc * 1024 + w * 512 + lane * 8);
        ph = __builtin_amdgcn_mfma_f32_16x16x32_bf16(afw, hh, ph, 0, 0, 0);
      }
      if (q == 0) {   // lane l16 = row-in-16, regs r = action 0..3
        f32x4 sc = *(const f32x4*)(stepsc + s * 4);
        f32x4 fb = *(const f32x4*)(finalb);
        f32x4 xv = *(const f32x4*)(lx + myrow * 4);
        f32x4 nz = *(const f32x4*)(noises + ((size_t)s * nb + rowbase + myrow) * 4);
        #pragma unroll
        for (int r = 0; r < 4; ++r) {
          float pr = ph[r] + fb[r];
          float v = (xv[r] - sc[1] * pr) * sc[0];
          xv[r] = fmaf(sc[2], nz[r], v);
        }
        *(f32x4*)(lx + myrow * 4) = xv;
      }
    }
    __syncthreads();
  }
  if (w < 2 && q == 0) {
    f32x4 xv = *(const f32x4*)(lx + myrow * 4);
    #pragma unroll
    for (int r = 0; r < 4; ++r) xv[r] = fminf(1.0f, fmaxf(-1.0f, xv[r]));
    *(f32x4*)(out + (size_t)(rowbase + myrow) * 4) = xv;
  }
}

// ---------------------------------------------------------------------------
extern "C" void kernel_launch(void* const* d_in, const int* in_sizes, int n_in,
                              void* d_out, int out_size, void* d_ws, size_t ws_size,
                              hipStream_t stream) {
  (void)n_in; (void)out_size; (void)ws_size;
  const float* features    = (const float*)d_in[0];
  const float* cond_w      = (const float*)d_in[1];
  const float* cond_b      = (const float*)d_in[2];
  const float* time_w      = (const float*)d_in[3];
  const float* time_b      = (const float*)d_in[4];
  const float* blk0_w1     = (const float*)d_in[5];
  const float* blk0_b1     = (const float*)d_in[6];
  const float* blk0_w2     = (const float*)d_in[7];
  const float* blk0_b2     = (const float*)d_in[8];
  const float* blk0_skip_w = (const float*)d_in[9];
  const float* blk0_skip_b = (const float*)d_in[10];
  const float* blks_w1     = (const float*)d_in[11];
  const float* blks_b1     = (const float*)d_in[12];
  const float* blks_w2     = (const float*)d_in[13];
  const float* blks_b2     = (const float*)d_in[14];
  const float* final_w     = (const float*)d_in[15];
  const float* final_b     = (const float*)d_in[16];

  const int nb = in_sizes[0] / 256;   // 32768

  char* ws = (char*)d_ws;
  bf16_t* wts    = (bf16_t*)(ws + 0);         // 1,310,720 B
  float*  tvecs  = (float*)(ws + 1310720);    // 20,480 B
  float*  stepsc = (float*)(ws + 1331200);    // 256 B
  float*  x0w    = (float*)(ws + 1331456);    // 524,288 B
  float*  noisew = (float*)(ws + 1855744);    // 5,242,880 B
  bf16_t* condf  = (bf16_t*)(ws + 7098624);   // 16,777,216 B
  bf16_t* fwf    = (bf16_t*)(ws + 23875840);  // 8,192 B

  wprep_kernel<<<2560, 256, 0, stream>>>(cond_w, blk0_w1, blk0_skip_w, blk0_w2,
                                         blks_w1, blks_w2, wts);
  ffp_kernel<<<16, 256, 0, stream>>>(final_w, fwf);
  prep_kernel<<<10, 256, 0, stream>>>(time_w, time_b, blk0_w1, blk0_b1,
                                      blk0_skip_w, blk0_skip_b, tvecs, stepsc);
  noise_kernel<<<(nb * 44 + 255) / 256, 256, 0, stream>>>(x0w, noisew, nb);
  cond_kernel<<<nb / 64, 256, 0, stream>>>(features, wts, cond_b, condf);
  fused_kernel<<<nb / 32, 256, 0, stream>>>(
      condf, wts, fwf, tvecs, stepsc, x0w, noisew,
      blk0_w1 + 512 * 256, blk0_skip_w + 512 * 256, blk0_b2,
      blks_b1, blks_b2, final_b, (float*)d_out, nb);
}

// Round 7
// 1006.333 us; speedup vs baseline: 1.7787x; 1.7787x over previous
//
#include <hip/hip_runtime.h>
#include <stdint.h>
#include <stddef.h>

// ---------------------------------------------------------------------------
// DiffusionActionHead: fused 10-step DDPM sampler, bf16 MFMA, round 7.
// MTILE=64 rows/block, 512 threads (8 waves), 1 block/CU (LDS ~97 KB).
// Each wave owns a 32-feature slice (mt 2 x nt 4 -> acc[8] = 32 VGPRs).
// cond staged in LDS once; activations in two frag-ordered LDS buffers;
// residual via own-cell readback. Weight fragments for the NEXT phase are
// prefetched into registers (pw[2][8], 64 VGPRs) during the current phase's
// epilogue, hiding L2 latency behind gelu + store + barrier.
// ---------------------------------------------------------------------------

typedef __bf16 bf16_t;
typedef __bf16 bf16x8 __attribute__((ext_vector_type(8)));
typedef __bf16 bf16x4 __attribute__((ext_vector_type(4)));
typedef float  f32x4  __attribute__((ext_vector_type(4)));

constexpr int KP = 264;   // LDS row stride for cond_kernel staging only

// ---------------- exact-erf GELU (A&S 7.1.26, |err|<1.5e-7) ----------------
__device__ __forceinline__ float gelu_f(float x) {
  float z  = 0.70710678f * x;
  float az = fabsf(z);
  float t  = __builtin_amdgcn_rcpf(fmaf(0.3275911f, az, 1.0f));
  float e  = __expf(-az * az);
  float p  = fmaf(1.061405429f, t, -1.453152027f);
  p = fmaf(p, t, 1.421413741f);
  p = fmaf(p, t, -0.284496736f);
  p = fmaf(p, t, 0.254829592f);
  float er = fmaf(-(p * t), e, 1.0f);   // erf(|z|)
  er = copysignf(er, z);
  return 0.5f * x * (1.0f + er);
}

// ---------------- JAX threefry2x32 (20 rounds) ------------------------------
#define TFR(a) x0 += x1; x1 = (x1 << (a)) | (x1 >> (32 - (a))); x1 ^= x0;
__device__ __forceinline__ void tf2(uint32_t k0, uint32_t k1,
                                    uint32_t x0, uint32_t x1,
                                    uint32_t& o0, uint32_t& o1) {
  uint32_t k2 = k0 ^ k1 ^ 0x1BD11BDAu;
  x0 += k0; x1 += k1;
  TFR(13) TFR(15) TFR(26) TFR(6)
  x0 += k1; x1 += k2 + 1u;
  TFR(17) TFR(29) TFR(16) TFR(24)
  x0 += k2; x1 += k0 + 2u;
  TFR(13) TFR(15) TFR(26) TFR(6)
  x0 += k0; x1 += k1 + 3u;
  TFR(17) TFR(29) TFR(16) TFR(24)
  x0 += k1; x1 += k2 + 4u;
  TFR(13) TFR(15) TFR(26) TFR(6)
  x0 += k2; x1 += k0 + 5u;
  o0 = x0; o1 = x1;
}
#undef TFR

// uniform bits -> N(0,1) exactly like jax.random.normal (XLA erfinv poly)
__device__ __forceinline__ float nrm_from_bits(uint32_t bits) {
  float f = __uint_as_float((bits >> 9) | 0x3f800000u) - 1.0f;  // [0,1)
  const float lo = -0.99999994f;
  float u = fmaxf(lo, __fadd_rn(__fmul_rn(f, 2.0f), lo));
  float w = -log1pf(-__fmul_rn(u, u));
  float p;
  if (w < 5.0f) {
    float ww = w - 2.5f;
    p = 2.81022636e-08f;
    p = fmaf(p, ww, 3.43273939e-07f);
    p = fmaf(p, ww, -3.5233877e-06f);
    p = fmaf(p, ww, -4.39150654e-06f);
    p = fmaf(p, ww, 0.00021858087f);
    p = fmaf(p, ww, -0.00125372503f);
    p = fmaf(p, ww, -0.00417768164f);
    p = fmaf(p, ww, 0.246640727f);
    p = fmaf(p, ww, 1.50140941f);
  } else {
    float ww = sqrtf(w) - 3.0f;
    p = -0.000200214257f;
    p = fmaf(p, ww, 0.000100950558f);
    p = fmaf(p, ww, 0.00134934322f);
    p = fmaf(p, ww, -0.00367342844f);
    p = fmaf(p, ww, 0.00573950773f);
    p = fmaf(p, ww, -0.0076224613f);
    p = fmaf(p, ww, 0.00943887047f);
    p = fmaf(p, ww, 1.00167406f);
    p = fmaf(p, ww, 2.83297682f);
  }
  return 1.41421354f * (p * u);
}

// ---------------- kernel 1: weight repack (A-frag order, m=feature) --------
__global__ void wprep_kernel(const float* __restrict__ condw,
                             const float* __restrict__ w1,
                             const float* __restrict__ skw,
                             const float* __restrict__ w2,
                             const float* __restrict__ bw1,
                             const float* __restrict__ bw2,
                             bf16_t* __restrict__ wts) {
  int e = blockIdx.x * 256 + threadIdx.x;
  int m = e >> 16;
  int r = e & 65535;
  int nt = r >> 12, kc = (r >> 9) & 7, lane = (r >> 3) & 63, j = r & 7;
  int n = nt * 16 + (lane & 15);
  int k = kc * 32 + (lane >> 4) * 8 + j;
  const float* src;
  if      (m == 0) src = condw;
  else if (m == 1) src = w1;                    // blk0_w1 rows 0..255 (cond)
  else if (m == 2) src = skw;                   // blk0_skip_w rows 0..255
  else if (m == 3) src = w2;                    // blk0_w2
  else if (m <= 6) src = bw1 + (m - 4) * 65536; // blks_w1[i]
  else             src = bw2 + (m - 7) * 65536; // blks_w2[i]
  wts[e] = (bf16_t)src[k * 256 + n];
}

// ---------------- kernel 1b: final_w A-frags (m=action, 12 cols zero) ------
__global__ void ffp_kernel(const float* __restrict__ fw, bf16_t* __restrict__ fwf) {
  int e = blockIdx.x * 256 + threadIdx.x;   // 4096 elems: [kc 8][lane 64][j 8]
  if (e >= 4096) return;
  int kc = e >> 9, lane = (e >> 3) & 63, j = e & 7;
  int l16 = lane & 15, q = lane >> 4;
  int k = kc * 32 + q * 8 + j;
  fwf[e] = (l16 < 4) ? (bf16_t)fw[k * 4 + l16] : (bf16_t)0.0f;
}

// ---------------- kernel 2: per-step vectors + scalars ---------------------
__global__ void prep_kernel(const float* __restrict__ time_w,
                            const float* __restrict__ time_b,
                            const float* __restrict__ w1,
                            const float* __restrict__ b1,
                            const float* __restrict__ skw,
                            const float* __restrict__ skb,
                            float* __restrict__ tvecs,
                            float* __restrict__ stepsc) {
  int s = blockIdx.x;          // 0..9, t = 90 - 10*s
  int j = threadIdx.x;
  int t = 90 - s * 10;
  float tval = (float)t;
  __shared__ float emb[256];
  __shared__ float temb[256];
  if (j < 128) {
    float freq = expf((float)j * -0.07252236513366287f);  // -ln(1e4)/127
    float e = tval * freq;
    emb[j] = sinf(e);
    emb[j + 128] = cosf(e);
  }
  __syncthreads();
  float a = time_b[j];
  for (int k = 0; k < 256; ++k) a = fmaf(emb[k], time_w[k * 256 + j], a);
  temb[j] = gelu_f(a);
  __syncthreads();
  float v1 = b1[j], v2 = skb[j];
  for (int k = 0; k < 256; ++k) {
    float tk = temb[k];
    v1 = fmaf(tk, w1[(256 + k) * 256 + j], v1);    // blk0_w1 rows 256..511
    v2 = fmaf(tk, skw[(256 + k) * 256 + j], v2);   // blk0_skip_w rows 256..511
  }
  tvecs[s * 512 + j] = v1;
  tvecs[s * 512 + 256 + j] = v2;
  if (j == 0) {
    float step = (0.02f - 1e-4f) / 99.0f;
    float acp = 1.0f, beta = 0.0f;
    for (int i = 0; i <= t; ++i) {
      beta = fmaf((float)i, step, 1e-4f);
      acp *= (1.0f - beta);
    }
    stepsc[s * 4 + 0] = 1.0f / sqrtf(1.0f - beta);   // 1/sqrt(alpha)
    stepsc[s * 4 + 1] = beta / sqrtf(1.0f - acp);    // b/sqrt(1-acp)
    stepsc[s * 4 + 2] = (t > 0) ? sqrtf(beta) : 0.0f;
    stepsc[s * 4 + 3] = 0.0f;
  }
}

// ---------------- kernel 3: x0 + noises (partitionable threefry) -----------
__global__ void noise_kernel(float* __restrict__ xout, float* __restrict__ nout, int nb) {
  int gid = blockIdx.x * 256 + threadIdx.x;
  int nx = nb * 4;
  int nn = nb * 40;
  uint32_t k0, k1, o0, o1;
  if (gid < nx) {
    tf2(0u, 42u, 0u, 999u, k0, k1);                 // fold_in(key(42), 999)
    tf2(k0, k1, 0u, (uint32_t)gid, o0, o1);
    xout[gid] = nrm_from_bits(o0 ^ o1);
  } else if (gid < nx + nn) {
    int i = gid - nx;
    tf2(0u, 42u, 0u, 7u, k0, k1);                   // fold_in(key(42), 7)
    tf2(k0, k1, 0u, (uint32_t)i, o0, o1);
    nout[i] = nrm_from_bits(o0 ^ o1);
  }
}

// ---------------- kernel 4: cond GEMM -> condf (B-frag packed, 64-row gran) -
// condf[rb][kc 8][nt 4][lane 64][j 8]: element = cond[row = rb*64+nt*16+(lane&15)]
//                                               [k   = kc*32+(lane>>4)*8+j]
__global__ __launch_bounds__(256, 2) void cond_kernel(
    const float* __restrict__ feat, const bf16_t* __restrict__ wts,
    const float* __restrict__ condb, bf16_t* __restrict__ condf) {
  __shared__ __align__(16) bf16_t la[64 * KP];
  const int tid = threadIdx.x;
  const int wave = tid >> 6, lane = tid & 63, quad = lane >> 4, l16 = lane & 15;
  const int rowbase = blockIdx.x * 64;
  for (int it = 0; it < 16; ++it) {
    int e = (it * 256 + tid) * 4;
    int rr = e >> 8, c = e & 255;
    f32x4 v = *(const f32x4*)(feat + (size_t)(rowbase + rr) * 256 + c);
    bf16x4 bv;
    bv[0] = (bf16_t)v[0]; bv[1] = (bf16_t)v[1];
    bv[2] = (bf16_t)v[2]; bv[3] = (bf16_t)v[3];
    *(bf16x4*)(la + rr * KP + c) = bv;
  }
  __syncthreads();
  f32x4 acc[16];
  #pragma unroll
  for (int i = 0; i < 16; ++i) acc[i] = f32x4{0.f, 0.f, 0.f, 0.f};
  const bf16_t* A = la + l16 * KP + quad * 8;
  const bf16_t* Wp = wts + wave * 16384 + lane * 8;
  #pragma unroll 2
  for (int kc = 0; kc < 8; ++kc) {
    bf16x8 a[4], b[4];
    #pragma unroll
    for (int rt = 0; rt < 4; ++rt) a[rt] = *(const bf16x8*)(A + rt * 16 * KP + kc * 32);
    #pragma unroll
    for (int ct = 0; ct < 4; ++ct) b[ct] = *(const bf16x8*)(Wp + ct * 4096 + kc * 512);
    #pragma unroll
    for (int rt = 0; rt < 4; ++rt)
      #pragma unroll
      for (int ct = 0; ct < 4; ++ct)
        acc[rt * 4 + ct] =
            __builtin_amdgcn_mfma_f32_16x16x32_bf16(a[rt], b[ct], acc[rt * 4 + ct], 0, 0, 0);
  }
  float bc[4];
  #pragma unroll
  for (int ct = 0; ct < 4; ++ct) bc[ct] = condb[wave * 64 + ct * 16 + l16];
  size_t base = (size_t)blockIdx.x * 16384;
  #pragma unroll
  for (int rt = 0; rt < 4; ++rt)
    #pragma unroll
    for (int r = 0; r < 4; ++r) {
      int l16f = quad * 4 + r;        // row-in-16 = quad*4+r; nt = rt
      #pragma unroll
      for (int ct = 0; ct < 4; ++ct) {
        int f = wave * 64 + ct * 16 + l16;     // feature = k index
        condf[base + (size_t)(f >> 5) * 2048 + (size_t)rt * 512 +
              (((f >> 3) & 3) * 16 + l16f) * 8 + (f & 7)] =
            (bf16_t)(acc[rt * 4 + ct][r] + bc[ct]);
      }
    }
}

// ---------------- kernel 5: fused 10-step sampler (512 thr, prefetch) ------
__global__ __launch_bounds__(512, 2) void fused_kernel(
    const bf16_t* __restrict__ condf, const bf16_t* __restrict__ wts,
    const bf16_t* __restrict__ fwf,
    const float* __restrict__ tvecs, const float* __restrict__ stepsc,
    const float* __restrict__ x0w, const float* __restrict__ noises,
    const float* __restrict__ w1bot, const float* __restrict__ skipbot,
    const float* __restrict__ b2v, const float* __restrict__ blksb1,
    const float* __restrict__ blksb2, const float* __restrict__ finalb,
    float* __restrict__ out, int nb) {
  // frag order [kc(8)][nt(4)][lane(64)][j(8)] = 16384 bf16 = 32 KB each
  __shared__ __align__(16) bf16_t condL[16384];
  __shared__ __align__(16) bf16_t bufY[16384];
  __shared__ __align__(16) bf16_t bufH[16384];
  __shared__ __align__(16) float  lx[256];
  const int tid = threadIdx.x;
  const int w = tid >> 6, lane = tid & 63, q = lane >> 4, l16 = lane & 15;
  const int rowbase = blockIdx.x * 64;
  const int myrow = w * 16 + l16;          // valid for waves 0..3 (head/x path)

  // stage cond tile (32 KB contiguous) + x0
  {
    const bf16_t* src = condf + (size_t)blockIdx.x * 16384;
    #pragma unroll
    for (int it = 0; it < 4; ++it) {
      int e = (it * 512 + tid) * 8;
      *(bf16x8*)(condL + e) = *(const bf16x8*)(src + e);
    }
    if (w < 4 && q == 0)
      *(f32x4*)(lx + myrow * 4) = *(const f32x4*)(x0w + (size_t)(rowbase + myrow) * 4);
  }
  __syncthreads();

  f32x4 acc[8];        // [mt 2][nt 4]
  bf16x8 pw[2][8];     // prefetched weight A-frags for the CURRENT phase

  // own-cell offsets: cell (mt,nt): features f0..f0+3, f0 = w*32+mt*16+q*4,
  // rows nt*16+l16 -> offset (f0>>5)*2048 + nt*512 + (((f0>>3)&3)*16+l16)*8 + (f0&7)
  int soff[2];
  #pragma unroll
  for (int mt = 0; mt < 2; ++mt) {
    int f0 = w * 32 + mt * 16 + q * 4;
    soff[mt] = (f0 >> 5) * 2048 + (((f0 >> 3) & 3) * 16 + l16) * 8 + (f0 & 7);
  }

  auto prefetch = [&](int L) {
    const bf16_t* wl = wts + (size_t)L * 65536 + (size_t)(w * 2) * 4096 + (size_t)lane * 8;
    #pragma unroll
    for (int kc = 0; kc < 8; ++kc) {
      pw[0][kc] = *(const bf16x8*)(wl + kc * 512);
      pw[1][kc] = *(const bf16x8*)(wl + 4096 + kc * 512);
    }
  };
  auto gemm_pw = [&](const bf16_t* act) {
    #pragma unroll
    for (int i = 0; i < 8; ++i) acc[i] = f32x4{0.f, 0.f, 0.f, 0.f};
    #pragma unroll
    for (int kc = 0; kc < 8; ++kc) {
      bf16x8 b[4];
      #pragma unroll
      for (int nt = 0; nt < 4; ++nt)
        b[nt] = *(const bf16x8*)(act + kc * 2048 + nt * 512 + lane * 8);
      #pragma unroll
      for (int mt = 0; mt < 2; ++mt)
        #pragma unroll
        for (int nt = 0; nt < 4; ++nt)
          acc[mt * 4 + nt] =
              __builtin_amdgcn_mfma_f32_16x16x32_bf16(pw[mt][kc], b[nt], acc[mt * 4 + nt], 0, 0, 0);
    }
  };
  auto store_act = [&](bf16_t* buf) {
    #pragma unroll
    for (int mt = 0; mt < 2; ++mt)
      #pragma unroll
      for (int nt = 0; nt < 4; ++nt) {
        f32x4 v = acc[mt * 4 + nt];
        bf16x4 bv;
        bv[0] = (bf16_t)v[0]; bv[1] = (bf16_t)v[1];
        bv[2] = (bf16_t)v[2]; bv[3] = (bf16_t)v[3];
        *(bf16x4*)(buf + soff[mt] + nt * 512) = bv;
      }
  };
  // acc += tvec + x @ Wbot (exact f32 x-path); optional gelu
  auto epi_bot = [&](const float* tv, const float* bot, bool dogelu) {
    f32x4 xr[4];
    #pragma unroll
    for (int nt = 0; nt < 4; ++nt) xr[nt] = *(const f32x4*)(lx + (nt * 16 + l16) * 4);
    #pragma unroll
    for (int mt = 0; mt < 2; ++mt) {
      int m = w * 32 + mt * 16 + q * 4;
      f32x4 tq = *(const f32x4*)(tv + m);
      f32x4 b0 = *(const f32x4*)(bot + m);
      f32x4 b1 = *(const f32x4*)(bot + 256 + m);
      f32x4 b2 = *(const f32x4*)(bot + 512 + m);
      f32x4 b3 = *(const f32x4*)(bot + 768 + m);
      #pragma unroll
      for (int nt = 0; nt < 4; ++nt)
        #pragma unroll
        for (int r = 0; r < 4; ++r) {
          float v = acc[mt * 4 + nt][r] + tq[r];
          v = fmaf(xr[nt][0], b0[r], v);
          v = fmaf(xr[nt][1], b1[r], v);
          v = fmaf(xr[nt][2], b2[r], v);
          v = fmaf(xr[nt][3], b3[r], v);
          acc[mt * 4 + nt][r] = dogelu ? gelu_f(v) : v;
        }
    }
  };
  auto epi_gelu = [&](const float* bias) {
    #pragma unroll
    for (int mt = 0; mt < 2; ++mt) {
      f32x4 bb = *(const f32x4*)(bias + w * 32 + mt * 16 + q * 4);
      #pragma unroll
      for (int nt = 0; nt < 4; ++nt)
        #pragma unroll
        for (int r = 0; r < 4; ++r)
          acc[mt * 4 + nt][r] = gelu_f(acc[mt * 4 + nt][r] + bb[r]);
    }
  };
  // h = gelu(acc + bias) + resid (own cells of buf)
  auto epi_gelu_res = [&](const float* bias, const bf16_t* buf) {
    #pragma unroll
    for (int mt = 0; mt < 2; ++mt) {
      f32x4 bb = *(const f32x4*)(bias + w * 32 + mt * 16 + q * 4);
      #pragma unroll
      for (int nt = 0; nt < 4; ++nt) {
        bf16x4 rv = *(const bf16x4*)(buf + soff[mt] + nt * 512);
        #pragma unroll
        for (int r = 0; r < 4; ++r)
          acc[mt * 4 + nt][r] = gelu_f(acc[mt * 4 + nt][r] + bb[r]) + (float)rv[r];
      }
    }
  };

  prefetch(1);   // W1 slice for the first phase
  for (int s = 0; s < 10; ++s) {
    const float* tw  = tvecs + s * 512;
    const float* tsk = tw + 256;

    // P1: y1 = gelu(W1_top·cond + tw1 + x·W1_bot)  -> bufY   (pw = L1)
    gemm_pw(condL);
    prefetch(2);
    epi_bot(tw, w1bot, true);
    store_act(bufY);
    // P2: skip = Wskip_top·cond + tskip + x·Wskip_bot -> bufH (pw = L2)
    gemm_pw(condL);
    prefetch(3);
    epi_bot(tsk, skipbot, false);
    store_act(bufH);
    __syncthreads();
    // P3: h = gelu(W2·y1 + b2) + skip              -> bufH   (pw = L3)
    gemm_pw(bufY);
    prefetch(4);
    epi_gelu_res(b2v, bufH);
    store_act(bufH);
    __syncthreads();
    // blocks 1..3
    #pragma unroll 1
    for (int blk = 0; blk < 3; ++blk) {
      gemm_pw(bufH);                      // pw = 4+blk
      prefetch(7 + blk);
      epi_gelu(blksb1 + blk * 256);
      store_act(bufY);
      __syncthreads();
      gemm_pw(bufY);                      // pw = 7+blk
      prefetch(blk < 2 ? 5 + blk : 1);    // next W1 slice wraps to next step
      epi_gelu_res(blksb2 + blk * 256, bufH);
      store_act(bufH);
      __syncthreads();
    }
    // head: pred = final_w^T · h  (waves 0..3: B = bufH frag nt=w)
    if (w < 4) {
      f32x4 ph = f32x4{0.f, 0.f, 0.f, 0.f};
      #pragma unroll
      for (int kc = 0; kc < 8; ++kc) {
        bf16x8 afw = *(const bf16x8*)(fwf + kc * 512 + lane * 8);
        bf16x8 hh  = *(const bf16x8*)(bufH + kc * 2048 + w * 512 + lane * 8);
        ph = __builtin_amdgcn_mfma_f32_16x16x32_bf16(afw, hh, ph, 0, 0, 0);
      }
      if (q == 0) {   // lane l16 = row-in-16 (nt=w), regs r = action 0..3
        f32x4 sc = *(const f32x4*)(stepsc + s * 4);
        f32x4 fb = *(const f32x4*)(finalb);
        f32x4 xv = *(const f32x4*)(lx + myrow * 4);
        f32x4 nz = *(const f32x4*)(noises + ((size_t)s * nb + rowbase + myrow) * 4);
        #pragma unroll
        for (int r = 0; r < 4; ++r) {
          float pr = ph[r] + fb[r];
          float v = (xv[r] - sc[1] * pr) * sc[0];
          xv[r] = fmaf(sc[2], nz[r], v);
        }
        *(f32x4*)(lx + myrow * 4) = xv;
      }
    }
    __syncthreads();
  }
  if (w < 4 && q == 0) {
    f32x4 xv = *(const f32x4*)(lx + myrow * 4);
    #pragma unroll
    for (int r = 0; r < 4; ++r) xv[r] = fminf(1.0f, fmaxf(-1.0f, xv[r]));
    *(f32x4*)(out + (size_t)(rowbase + myrow) * 4) = xv;
  }
}

// ---------------------------------------------------------------------------
extern "C" void kernel_launch(void* const* d_in, const int* in_sizes, int n_in,
                              void* d_out, int out_size, void* d_ws, size_t ws_size,
                              hipStream_t stream) {
  (void)n_in; (void)out_size; (void)ws_size;
  const float* features    = (const float*)d_in[0];
  const float* cond_w      = (const float*)d_in[1];
  const float* cond_b      = (const float*)d_in[2];
  const float* time_w      = (const float*)d_in[3];
  const float* time_b      = (const float*)d_in[4];
  const float* blk0_w1     = (const float*)d_in[5];
  const float* blk0_b1     = (const float*)d_in[6];
  const float* blk0_w2     = (const float*)d_in[7];
  const float* blk0_b2     = (const float*)d_in[8];
  const float* blk0_skip_w = (const float*)d_in[9];
  const float* blk0_skip_b = (const float*)d_in[10];
  const float* blks_w1     = (const float*)d_in[11];
  const float* blks_b1     = (const float*)d_in[12];
  const float* blks_w2     = (const float*)d_in[13];
  const float* blks_b2     = (const float*)d_in[14];
  const float* final_w     = (const float*)d_in[15];
  const float* final_b     = (const float*)d_in[16];

  const int nb = in_sizes[0] / 256;   // 32768

  char* ws = (char*)d_ws;
  bf16_t* wts    = (bf16_t*)(ws + 0);         // 1,310,720 B
  float*  tvecs  = (float*)(ws + 1310720);    // 20,480 B
  float*  stepsc = (float*)(ws + 1331200);    // 256 B
  float*  x0w    = (float*)(ws + 1331456);    // 524,288 B
  float*  noisew = (float*)(ws + 1855744);    // 5,242,880 B
  bf16_t* condf  = (bf16_t*)(ws + 7098624);   // 16,777,216 B
  bf16_t* fwf    = (bf16_t*)(ws + 23875840);  // 8,192 B

  wprep_kernel<<<2560, 256, 0, stream>>>(cond_w, blk0_w1, blk0_skip_w, blk0_w2,
                                         blks_w1, blks_w2, wts);
  ffp_kernel<<<16, 256, 0, stream>>>(final_w, fwf);
  prep_kernel<<<10, 256, 0, stream>>>(time_w, time_b, blk0_w1, blk0_b1,
                                      blk0_skip_w, blk0_skip_b, tvecs, stepsc);
  noise_kernel<<<(nb * 44 + 255) / 256, 256, 0, stream>>>(x0w, noisew, nb);
  cond_kernel<<<nb / 64, 256, 0, stream>>>(features, wts, cond_b, condf);
  fused_kernel<<<nb / 64, 512, 0, stream>>>(
      condf, wts, fwf, tvecs, stepsc, x0w, noisew,
      blk0_w1 + 512 * 256, blk0_skip_w + 512 * 256, blk0_b2,
      blks_b1, blks_b2, final_b, (float*)d_out, nb);
}